// Round 7
// baseline (552.459 us; speedup 1.0000x reference)
//
#include <hip/hip_runtime.h>

#define N_NODES 50000
#define N_EDGES 600000
#define DIM 128
#define N_LAYERS 4
#define N_GRAPHS 64
#define NEG_SLOPE 0.01f
#define NB_SCAN ((N_NODES + 255) / 256)  // 196 blocks
#define RS 264  // LDS row stride in bf16 elems: 256 data + 8 pad (16B)

typedef __attribute__((ext_vector_type(8))) short short8;
typedef __attribute__((ext_vector_type(16))) float floatx16;

__device__ __forceinline__ unsigned short f2bf(float f) {
    union { float f; unsigned u; } c; c.f = f;
    unsigned u = c.u;
    unsigned r = (u + 0x7FFFu + ((u >> 16) & 1u)) >> 16;
    return (unsigned short)r;
}
__device__ __forceinline__ float bfraw2f(unsigned short b) {
    union { unsigned u; float f; } c; c.u = ((unsigned)b) << 16;
    return c.f;
}
__device__ __forceinline__ float bflo(unsigned u) {
    union { unsigned u; float f; } c; c.u = u << 16; return c.f;
}
__device__ __forceinline__ float bfhi(unsigned u) {
    union { unsigned u; float f; } c; c.u = u & 0xFFFF0000u; return c.f;
}

// ---------------- utility kernels ----------------

__global__ void zero_ints(int* p, int n) {
    int i = blockIdx.x * blockDim.x + threadIdx.x;
    if (i < n) p[i] = 0;
}

// convert fp32 x -> bf16 (8 elems per thread)
__global__ void convert_x(const float4* __restrict__ x, uint4* __restrict__ xb) {
    int i = blockIdx.x * blockDim.x + threadIdx.x;  // chunk of 8 floats
    if (i >= N_NODES * DIM / 8) return;
    float4 a = x[i * 2], b = x[i * 2 + 1];
    uint4 o;
    o.x = ((unsigned)f2bf(a.y) << 16) | f2bf(a.x);
    o.y = ((unsigned)f2bf(a.w) << 16) | f2bf(a.z);
    o.z = ((unsigned)f2bf(b.y) << 16) | f2bf(b.x);
    o.w = ((unsigned)f2bf(b.w) << 16) | f2bf(b.z);
    xb[i] = o;
}

// pack weights into MFMA B-fragment order (bf16), for v_mfma_f32_32x32x16_bf16.
// B[k][n] = W[n][k]. Fragment (layer, m, s, t): lane l holds B[s*16+(l>>5)*8+j][t*32+(l&31)], j=0..7.
__global__ void pack_w(const float* __restrict__ Wl, const float* __restrict__ Wr,
                       ushort* __restrict__ wpk) {
    int s = blockIdx.x >> 2, t = blockIdx.x & 3;
    int m = blockIdx.y, layer = blockIdx.z;
    int l = threadIdx.x;  // 64 lanes
    const float* W = ((m == 0) ? Wl : Wr) + (size_t)layer * DIM * DIM;
    int n = t * 32 + (l & 31);
    int kb = s * 16 + (l >> 5) * 8;
    size_t off = ((((size_t)(layer * 2 + m) * 8 + s) * 4 + t) * 64 + l) * 8;
    for (int j = 0; j < 8; j++)
        wpk[off + j] = f2bf(W[n * DIM + kb + j]);
}

__global__ void count_deg(const int* __restrict__ dst, int* deg) {
    int e = blockIdx.x * blockDim.x + threadIdx.x;
    if (e < N_EDGES) atomicAdd(&deg[dst[e]], 1);
}

// ---------------- 3-pass exclusive scan of deg -> rp ----------------
__global__ void scan_pass1(const int* __restrict__ deg, int* __restrict__ bsum) {
    int i = blockIdx.x * 256 + threadIdx.x;
    int v = (i < N_NODES) ? deg[i] : 0;
    for (int off = 32; off > 0; off >>= 1) v += __shfl_down(v, off, 64);
    __shared__ int ws[4];
    int lane = threadIdx.x & 63, w = threadIdx.x >> 6;
    if (lane == 0) ws[w] = v;
    __syncthreads();
    if (threadIdx.x == 0) bsum[blockIdx.x] = ws[0] + ws[1] + ws[2] + ws[3];
}

__global__ void scan_pass2(int* __restrict__ bsum) {
    __shared__ int sm[256];
    int t = threadIdx.x;
    int v = (t < NB_SCAN) ? bsum[t] : 0;
    sm[t] = v;
    __syncthreads();
    for (int off = 1; off < 256; off <<= 1) {
        int u = (t >= off) ? sm[t - off] : 0;
        __syncthreads();
        sm[t] += u;
        __syncthreads();
    }
    if (t < NB_SCAN) bsum[t] = sm[t] - v;
}

__global__ void scan_pass3(const int* __restrict__ deg, const int* __restrict__ bsum,
                           int* __restrict__ rp) {
    int i = blockIdx.x * 256 + threadIdx.x;
    int v = (i < N_NODES) ? deg[i] : 0;
    int lane = threadIdx.x & 63, w = threadIdx.x >> 6;
    int s = v;
    for (int off = 1; off < 64; off <<= 1) {
        int t = __shfl_up(s, off, 64);
        if (lane >= off) s += t;
    }
    __shared__ int ws[4];
    if (lane == 63) ws[w] = s;
    __syncthreads();
    int wo = 0;
    for (int k = 0; k < 4; k++) wo += (k < w) ? ws[k] : 0;
    int incl = s + wo + bsum[blockIdx.x];
    if (i < N_NODES) rp[i + 1] = incl;
    if (i == 0) rp[0] = 0;
}

__global__ void fill_csr(const int* __restrict__ src, const int* __restrict__ dst,
                         const int* __restrict__ rp, int* __restrict__ fill,
                         int* __restrict__ csr) {
    int e = blockIdx.x * blockDim.x + threadIdx.x;
    if (e >= N_EDGES) return;
    int d = dst[e];
    int pos = atomicAdd(&fill[d], 1);
    csr[rp[d] + pos] = src[e];
}

__global__ void graph_start(const int* __restrict__ batch, int* __restrict__ gstart) {
    int i = blockIdx.x * blockDim.x + threadIdx.x;
    if (i >= N_NODES) return;
    int b = batch[i];
    if (i == 0) {
        for (int g = 0; g <= b; g++) gstart[g] = 0;
    } else {
        int p = batch[i - 1];
        for (int g = p + 1; g <= b; g++) gstart[g] = i;
    }
    if (i == N_NODES - 1) {
        for (int g = b + 1; g <= N_GRAPHS; g++) gstart[g] = N_NODES;
    }
}

// ---------------- aggregation: pass-split gather for L2 residency ----------------
// grid (ceil(N/4), 4): blockIdx.y = pass p covers dim-quarter [32p, 32p+32) (one 64B
// line per edge). Live footprint per pass = 3.2 MB < 4 MiB XCD-L2 -> gathers hit L2.
// Wave per node; lane = e16*4 + q : e16 = edge slot (16 edges/iter), q = 16B chunk.
__global__ __launch_bounds__(256) void agg_pass(const uint4* __restrict__ x16B,
                                                const int* __restrict__ rp,
                                                const int* __restrict__ csr,
                                                uint4* __restrict__ agg16B) {
    int wv = threadIdx.x >> 6, lane = threadIdx.x & 63;
    int node = blockIdx.x * 4 + wv;
    int p = blockIdx.y;
    if (node >= N_NODES) return;
    int s = rp[node], e = rp[node + 1];
    int e16 = lane >> 2, q = lane & 3;
    float a0 = 0.f, a1 = 0.f, a2 = 0.f, a3 = 0.f, a4 = 0.f, a5 = 0.f, a6 = 0.f, a7 = 0.f;
    for (int base = s; base < e; base += 16) {
        int ei = base + e16;
        uint4 v = make_uint4(0u, 0u, 0u, 0u);
        if (ei < e) {
            unsigned idx = (unsigned)csr[ei];
            v = x16B[(size_t)idx * 16 + p * 4 + q];
        }
        a0 += bflo(v.x); a1 += bfhi(v.x);
        a2 += bflo(v.y); a3 += bfhi(v.y);
        a4 += bflo(v.z); a5 += bfhi(v.z);
        a6 += bflo(v.w); a7 += bfhi(v.w);
    }
    // reduce across the 16 edge slots (lanes differing in bits 2..5)
#pragma unroll
    for (int off = 4; off < 64; off <<= 1) {
        a0 += __shfl_xor(a0, off, 64); a1 += __shfl_xor(a1, off, 64);
        a2 += __shfl_xor(a2, off, 64); a3 += __shfl_xor(a3, off, 64);
        a4 += __shfl_xor(a4, off, 64); a5 += __shfl_xor(a5, off, 64);
        a6 += __shfl_xor(a6, off, 64); a7 += __shfl_xor(a7, off, 64);
    }
    if (e16 == 0) {
        float inv = 1.0f / (float)max(e - s, 1);
        uint4 o;
        o.x = ((unsigned)f2bf(a1 * inv) << 16) | f2bf(a0 * inv);
        o.y = ((unsigned)f2bf(a3 * inv) << 16) | f2bf(a2 * inv);
        o.z = ((unsigned)f2bf(a5 * inv) << 16) | f2bf(a4 * inv);
        o.w = ((unsigned)f2bf(a7 * inv) << 16) | f2bf(a6 * inv);
        agg16B[(size_t)node * 16 + p * 4 + q] = o;
    }
}

// ---------------- fused dual-GEMM layer, MFMA bf16 ----------------
__global__ __launch_bounds__(256) void fused_layer_mfma(const ushort* __restrict__ agg,
                                                        const ushort* __restrict__ xin,
                                                        ushort* __restrict__ xout,
                                                        const ushort* __restrict__ wpk,
                                                        const float* __restrict__ bias,
                                                        int residual) {
    __shared__ ushort sA[128 * RS];  // row r: [agg(128) | x(128) | pad(8)]
    int t = threadIdx.x;
    int node0 = blockIdx.x * 128;

    const uint4* aggv = (const uint4*)(agg + (size_t)node0 * DIM);
    const uint4* xv   = (const uint4*)(xin + (size_t)node0 * DIM);
    for (int i = t; i < 128 * 32; i += 256) {
        int r = i >> 5, c = i & 31;
        uint4 val = make_uint4(0u, 0u, 0u, 0u);
        if (node0 + r < N_NODES)
            val = (c < 16) ? aggv[r * 16 + c] : xv[r * 16 + (c - 16)];
        *(uint4*)&sA[r * RS + c * 8] = val;
    }
    __syncthreads();

    int wv = t >> 6, l = t & 63;
    int m0 = wv * 32;
    const ushort* arow = &sA[(m0 + (l & 31)) * RS];
    int khalf = (l >> 5) * 8;

    floatx16 acc0, acc1, acc2, acc3;
    for (int ii = 0; ii < 16; ii++) acc0[ii] = acc1[ii] = acc2[ii] = acc3[ii] = 0.f;

    const ushort* wl8 = wpk + (size_t)l * 8;
#pragma unroll
    for (int s2 = 0; s2 < 16; s2++) {
        int m = s2 >> 3, s = s2 & 7;
        short8 a = *(const short8*)(arow + m * 128 + s * 16 + khalf);
        size_t fb = (size_t)((m * 8 + s) * 4) * 512;
        short8 b0 = *(const short8*)(wl8 + fb);
        short8 b1 = *(const short8*)(wl8 + fb + 512);
        short8 b2 = *(const short8*)(wl8 + fb + 1024);
        short8 b3 = *(const short8*)(wl8 + fb + 1536);
        acc0 = __builtin_amdgcn_mfma_f32_32x32x16_bf16(a, b0, acc0, 0, 0, 0);
        acc1 = __builtin_amdgcn_mfma_f32_32x32x16_bf16(a, b1, acc1, 0, 0, 0);
        acc2 = __builtin_amdgcn_mfma_f32_32x32x16_bf16(a, b2, acc2, 0, 0, 0);
        acc3 = __builtin_amdgcn_mfma_f32_32x32x16_bf16(a, b3, acc3, 0, 0, 0);
    }

    int col = l & 31;
    int rbase = 4 * (l >> 5);
    floatx16 accs[4] = {acc0, acc1, acc2, acc3};
    for (int t4 = 0; t4 < 4; t4++) {
        int n = t4 * 32 + col;
        float bv = bias[n];
#pragma unroll
        for (int r = 0; r < 16; r++) {
            int row = (r & 3) + 8 * (r >> 2) + rbase;
            int gm = m0 + row;
            int gn = node0 + gm;
            if (gn >= N_NODES) continue;
            float v = accs[t4][r] + bv;
            v = (v >= 0.f) ? v : NEG_SLOPE * v;
            if (residual) v += bfraw2f(sA[gm * RS + 128 + n]);
            xout[(size_t)gn * DIM + n] = f2bf(v);
        }
    }
}

// ---------------- global mean pool, parallel segment-sum ----------------
__global__ __launch_bounds__(128) void pool_partial(const ushort* __restrict__ xb,
                                                    const int* __restrict__ batch,
                                                    float* __restrict__ pooled) {
    int nb = blockIdx.x * 128;
    int ne = min(nb + 128, N_NODES);
    int d = threadIdx.x;
    int gcur = batch[nb];
    float acc = 0.f;
    for (int n = nb; n < ne; n++) {
        int g = batch[n];
        if (g != gcur) {
            atomicAdd(&pooled[gcur * DIM + d], acc);
            acc = 0.f;
            gcur = g;
        }
        acc += bfraw2f(xb[(size_t)n * DIM + d]);
    }
    atomicAdd(&pooled[gcur * DIM + d], acc);
}

__global__ void pool_final(const float* __restrict__ pooled,
                           const int* __restrict__ gstart,
                           float* __restrict__ out) {
    int i = blockIdx.x * blockDim.x + threadIdx.x;
    if (i >= N_GRAPHS * DIM) return;
    int g = i >> 7;
    int cnt = gstart[g + 1] - gstart[g];
    out[i] = pooled[i] / (float)max(cnt, 1);
}

// ---------------- launch ----------------

extern "C" void kernel_launch(void* const* d_in, const int* in_sizes, int n_in,
                              void* d_out, int out_size, void* d_ws, size_t ws_size,
                              hipStream_t stream) {
    const float* x     = (const float*)d_in[0];
    const int*   ei    = (const int*)d_in[1];
    const int*   batch = (const int*)d_in[2];
    const float* Wl    = (const float*)d_in[3];
    const float* bl    = (const float*)d_in[4];
    const float* Wr    = (const float*)d_in[5];
    float* out = (float*)d_out;

    const int* esrc = ei;
    const int* edst = ei + N_EDGES;

    // workspace layout
    ushort* xb0  = (ushort*)d_ws;                         // [N,128] bf16
    ushort* xbuf = xb0 + (size_t)N_NODES * DIM;           // [N,128] bf16
    ushort* agg  = xbuf + (size_t)N_NODES * DIM;          // [N,128] bf16
    ushort* wpk  = agg + (size_t)N_NODES * DIM;           // [4][2][128*128] bf16
    int* deg    = (int*)(wpk + (size_t)N_LAYERS * 2 * DIM * DIM);
    int* fill   = deg + N_NODES;
    int* csr    = fill + N_NODES;
    int* rp     = csr + N_EDGES;
    int* gstart = rp + (N_NODES + 1);
    int* bsum   = gstart + (N_GRAPHS + 1);
    float* pooled = (float*)(bsum + NB_SCAN);             // [G,128] fp32

    zero_ints<<<(2 * N_NODES + 255) / 256, 256, 0, stream>>>(deg, 2 * N_NODES);
    zero_ints<<<(N_GRAPHS * DIM + 255) / 256, 256, 0, stream>>>((int*)pooled, N_GRAPHS * DIM);

    convert_x<<<(N_NODES * DIM / 8 + 255) / 256, 256, 0, stream>>>((const float4*)x, (uint4*)xb0);
    pack_w<<<dim3(32, 2, 4), 64, 0, stream>>>(Wl, Wr, wpk);
    count_deg<<<(N_EDGES + 255) / 256, 256, 0, stream>>>(edst, deg);

    scan_pass1<<<NB_SCAN, 256, 0, stream>>>(deg, bsum);
    scan_pass2<<<1, 256, 0, stream>>>(bsum);
    scan_pass3<<<NB_SCAN, 256, 0, stream>>>(deg, bsum, rp);

    fill_csr<<<(N_EDGES + 255) / 256, 256, 0, stream>>>(esrc, edst, rp, fill, csr);
    graph_start<<<(N_NODES + 255) / 256, 256, 0, stream>>>(batch, gstart);

    int aggx = (N_NODES + 3) / 4;   // wave per node, 4 passes in grid.y
    int gemm_blocks = (N_NODES + 127) / 128;
    for (int l = 0; l < N_LAYERS; l++) {
        const ushort* xin = (l == 0) ? xb0 : xbuf;
        agg_pass<<<dim3(aggx, 4), 256, 0, stream>>>((const uint4*)xin, rp, csr, (uint4*)agg);
        fused_layer_mfma<<<gemm_blocks, 256, 0, stream>>>(
            agg, xin, xbuf, wpk + (size_t)l * 2 * DIM * DIM,
            bl + (size_t)l * DIM, (l >= 2) ? 1 : 0);
    }

    pool_partial<<<(N_NODES + 127) / 128, 128, 0, stream>>>(xbuf, batch, pooled);
    pool_final<<<(N_GRAPHS * DIM + 255) / 256, 256, 0, stream>>>(pooled, gstart, out);
}

// Round 8
// 367.484 us; speedup vs baseline: 1.5034x; 1.5034x over previous
//
#include <hip/hip_runtime.h>

#define N_NODES 50000
#define N_EDGES 600000
#define DIM 128
#define N_LAYERS 4
#define N_GRAPHS 64
#define NEG_SLOPE 0.01f
#define NB_SCAN ((N_NODES + 255) / 256)  // 196 blocks
#define RS 264  // LDS row stride in bf16 elems: 256 data + 8 pad (16B)

typedef __attribute__((ext_vector_type(8))) short short8;
typedef __attribute__((ext_vector_type(16))) float floatx16;

__device__ __forceinline__ unsigned short f2bf(float f) {
    union { float f; unsigned u; } c; c.f = f;
    unsigned u = c.u;
    unsigned r = (u + 0x7FFFu + ((u >> 16) & 1u)) >> 16;
    return (unsigned short)r;
}
__device__ __forceinline__ float bfraw2f(unsigned short b) {
    union { unsigned u; float f; } c; c.u = ((unsigned)b) << 16;
    return c.f;
}
__device__ __forceinline__ float bflo(unsigned u) {
    union { unsigned u; float f; } c; c.u = u << 16; return c.f;
}
__device__ __forceinline__ float bfhi(unsigned u) {
    union { unsigned u; float f; } c; c.u = u & 0xFFFF0000u; return c.f;
}

// ---------------- utility kernels ----------------

__global__ void zero_ints(int* p, int n) {
    int i = blockIdx.x * blockDim.x + threadIdx.x;
    if (i < n) p[i] = 0;
}

// convert fp32 x -> bf16 (8 elems per thread)
__global__ void convert_x(const float4* __restrict__ x, uint4* __restrict__ xb) {
    int i = blockIdx.x * blockDim.x + threadIdx.x;  // chunk of 8 floats
    if (i >= N_NODES * DIM / 8) return;
    float4 a = x[i * 2], b = x[i * 2 + 1];
    uint4 o;
    o.x = ((unsigned)f2bf(a.y) << 16) | f2bf(a.x);
    o.y = ((unsigned)f2bf(a.w) << 16) | f2bf(a.z);
    o.z = ((unsigned)f2bf(b.y) << 16) | f2bf(b.x);
    o.w = ((unsigned)f2bf(b.w) << 16) | f2bf(b.z);
    xb[i] = o;
}

// pack weights into MFMA B-fragment order (bf16), for v_mfma_f32_32x32x16_bf16.
// B[k][n] = W[n][k]. Fragment (layer, m, s, t): lane l holds B[s*16+(l>>5)*8+j][t*32+(l&31)], j=0..7.
__global__ void pack_w(const float* __restrict__ Wl, const float* __restrict__ Wr,
                       ushort* __restrict__ wpk) {
    int s = blockIdx.x >> 2, t = blockIdx.x & 3;
    int m = blockIdx.y, layer = blockIdx.z;
    int l = threadIdx.x;  // 64 lanes
    const float* W = ((m == 0) ? Wl : Wr) + (size_t)layer * DIM * DIM;
    int n = t * 32 + (l & 31);
    int kb = s * 16 + (l >> 5) * 8;
    size_t off = ((((size_t)(layer * 2 + m) * 8 + s) * 4 + t) * 64 + l) * 8;
    for (int j = 0; j < 8; j++)
        wpk[off + j] = f2bf(W[n * DIM + kb + j]);
}

__global__ void count_deg(const int* __restrict__ dst, int* deg) {
    int e = blockIdx.x * blockDim.x + threadIdx.x;
    if (e < N_EDGES) atomicAdd(&deg[dst[e]], 1);
}

// ---------------- 3-pass exclusive scan of deg -> rp ----------------
__global__ void scan_pass1(const int* __restrict__ deg, int* __restrict__ bsum) {
    int i = blockIdx.x * 256 + threadIdx.x;
    int v = (i < N_NODES) ? deg[i] : 0;
    for (int off = 32; off > 0; off >>= 1) v += __shfl_down(v, off, 64);
    __shared__ int ws[4];
    int lane = threadIdx.x & 63, w = threadIdx.x >> 6;
    if (lane == 0) ws[w] = v;
    __syncthreads();
    if (threadIdx.x == 0) bsum[blockIdx.x] = ws[0] + ws[1] + ws[2] + ws[3];
}

__global__ void scan_pass2(int* __restrict__ bsum) {
    __shared__ int sm[256];
    int t = threadIdx.x;
    int v = (t < NB_SCAN) ? bsum[t] : 0;
    sm[t] = v;
    __syncthreads();
    for (int off = 1; off < 256; off <<= 1) {
        int u = (t >= off) ? sm[t - off] : 0;
        __syncthreads();
        sm[t] += u;
        __syncthreads();
    }
    if (t < NB_SCAN) bsum[t] = sm[t] - v;
}

__global__ void scan_pass3(const int* __restrict__ deg, const int* __restrict__ bsum,
                           int* __restrict__ rp) {
    int i = blockIdx.x * 256 + threadIdx.x;
    int v = (i < N_NODES) ? deg[i] : 0;
    int lane = threadIdx.x & 63, w = threadIdx.x >> 6;
    int s = v;
    for (int off = 1; off < 64; off <<= 1) {
        int t = __shfl_up(s, off, 64);
        if (lane >= off) s += t;
    }
    __shared__ int ws[4];
    if (lane == 63) ws[w] = s;
    __syncthreads();
    int wo = 0;
    for (int k = 0; k < 4; k++) wo += (k < w) ? ws[k] : 0;
    int incl = s + wo + bsum[blockIdx.x];
    if (i < N_NODES) rp[i + 1] = incl;
    if (i == 0) rp[0] = 0;
}

__global__ void fill_csr(const int* __restrict__ src, const int* __restrict__ dst,
                         const int* __restrict__ rp, int* __restrict__ fill,
                         int* __restrict__ csr) {
    int e = blockIdx.x * blockDim.x + threadIdx.x;
    if (e >= N_EDGES) return;
    int d = dst[e];
    int pos = atomicAdd(&fill[d], 1);
    csr[rp[d] + pos] = src[e];
}

__global__ void graph_start(const int* __restrict__ batch, int* __restrict__ gstart) {
    int i = blockIdx.x * blockDim.x + threadIdx.x;
    if (i >= N_NODES) return;
    int b = batch[i];
    if (i == 0) {
        for (int g = 0; g <= b; g++) gstart[g] = 0;
    } else {
        int p = batch[i - 1];
        for (int g = p + 1; g <= b; g++) gstart[g] = i;
    }
    if (i == N_NODES - 1) {
        for (int g = b + 1; g <= N_GRAPHS; g++) gstart[g] = N_NODES;
    }
}

// ---------------- aggregation: wave per node, dwordx4 gather, 4 loads in flight ----
// lane = eg*16 + ll : eg selects edge within group-of-4, ll = 16B chunk of the 256B row.
// One dwordx4 wave-load fetches 4 complete neighbor rows (16 cache lines).
__global__ __launch_bounds__(256) void agg_mean_wave4(const uint4* __restrict__ x16B,
                                                      const int* __restrict__ rp,
                                                      const int* __restrict__ csr,
                                                      uint4* __restrict__ agg16B) {
    int wv = threadIdx.x >> 6, lane = threadIdx.x & 63;
    int node = blockIdx.x * 4 + wv;
    if (node >= N_NODES) return;
    int s = rp[node], e = rp[node + 1];
    int ll = lane & 15, eg = lane >> 4;
    float a0 = 0.f, a1 = 0.f, a2 = 0.f, a3 = 0.f, a4 = 0.f, a5 = 0.f, a6 = 0.f, a7 = 0.f;
    for (int base = s; base < e; base += 64) {
        int cnt = min(64, e - base);
        unsigned myidx = (base + lane < e) ? (unsigned)csr[base + lane] : 0u;
        for (int j = 0; j < cnt; j += 16) {
            uint4 v[4];
#pragma unroll
            for (int k = 0; k < 4; k++) {
                int sel = j + k * 4 + eg;                 // <= 63 always
                unsigned idx = __shfl(myidx, sel, 64);
                v[k] = make_uint4(0u, 0u, 0u, 0u);
                if (sel < cnt) v[k] = x16B[(size_t)idx * 16 + ll];
            }
#pragma unroll
            for (int k = 0; k < 4; k++) {
                a0 += bflo(v[k].x); a1 += bfhi(v[k].x);
                a2 += bflo(v[k].y); a3 += bfhi(v[k].y);
                a4 += bflo(v[k].z); a5 += bfhi(v[k].z);
                a6 += bflo(v[k].w); a7 += bfhi(v[k].w);
            }
        }
    }
    // reduce across the 4 edge-groups (lane^16, lane^32)
    a0 += __shfl_xor(a0, 16, 64); a0 += __shfl_xor(a0, 32, 64);
    a1 += __shfl_xor(a1, 16, 64); a1 += __shfl_xor(a1, 32, 64);
    a2 += __shfl_xor(a2, 16, 64); a2 += __shfl_xor(a2, 32, 64);
    a3 += __shfl_xor(a3, 16, 64); a3 += __shfl_xor(a3, 32, 64);
    a4 += __shfl_xor(a4, 16, 64); a4 += __shfl_xor(a4, 32, 64);
    a5 += __shfl_xor(a5, 16, 64); a5 += __shfl_xor(a5, 32, 64);
    a6 += __shfl_xor(a6, 16, 64); a6 += __shfl_xor(a6, 32, 64);
    a7 += __shfl_xor(a7, 16, 64); a7 += __shfl_xor(a7, 32, 64);
    if (eg == 0) {
        float inv = 1.0f / (float)max(e - s, 1);
        uint4 o;
        o.x = ((unsigned)f2bf(a1 * inv) << 16) | f2bf(a0 * inv);
        o.y = ((unsigned)f2bf(a3 * inv) << 16) | f2bf(a2 * inv);
        o.z = ((unsigned)f2bf(a5 * inv) << 16) | f2bf(a4 * inv);
        o.w = ((unsigned)f2bf(a7 * inv) << 16) | f2bf(a6 * inv);
        agg16B[(size_t)node * 16 + ll] = o;
    }
}

// ---------------- fused dual-GEMM layer, MFMA bf16 ----------------
__global__ __launch_bounds__(256) void fused_layer_mfma(const ushort* __restrict__ agg,
                                                        const ushort* __restrict__ xin,
                                                        ushort* __restrict__ xout,
                                                        const ushort* __restrict__ wpk,
                                                        const float* __restrict__ bias,
                                                        int residual) {
    __shared__ ushort sA[128 * RS];  // row r: [agg(128) | x(128) | pad(8)]
    int t = threadIdx.x;
    int node0 = blockIdx.x * 128;

    const uint4* aggv = (const uint4*)(agg + (size_t)node0 * DIM);
    const uint4* xv   = (const uint4*)(xin + (size_t)node0 * DIM);
    for (int i = t; i < 128 * 32; i += 256) {
        int r = i >> 5, c = i & 31;
        uint4 val = make_uint4(0u, 0u, 0u, 0u);
        if (node0 + r < N_NODES)
            val = (c < 16) ? aggv[r * 16 + c] : xv[r * 16 + (c - 16)];
        *(uint4*)&sA[r * RS + c * 8] = val;
    }
    __syncthreads();

    int wv = t >> 6, l = t & 63;
    int m0 = wv * 32;
    const ushort* arow = &sA[(m0 + (l & 31)) * RS];
    int khalf = (l >> 5) * 8;

    floatx16 acc0, acc1, acc2, acc3;
    for (int ii = 0; ii < 16; ii++) acc0[ii] = acc1[ii] = acc2[ii] = acc3[ii] = 0.f;

    const ushort* wl8 = wpk + (size_t)l * 8;
#pragma unroll
    for (int s2 = 0; s2 < 16; s2++) {
        int m = s2 >> 3, s = s2 & 7;
        short8 a = *(const short8*)(arow + m * 128 + s * 16 + khalf);
        size_t fb = (size_t)((m * 8 + s) * 4) * 512;
        short8 b0 = *(const short8*)(wl8 + fb);
        short8 b1 = *(const short8*)(wl8 + fb + 512);
        short8 b2 = *(const short8*)(wl8 + fb + 1024);
        short8 b3 = *(const short8*)(wl8 + fb + 1536);
        acc0 = __builtin_amdgcn_mfma_f32_32x32x16_bf16(a, b0, acc0, 0, 0, 0);
        acc1 = __builtin_amdgcn_mfma_f32_32x32x16_bf16(a, b1, acc1, 0, 0, 0);
        acc2 = __builtin_amdgcn_mfma_f32_32x32x16_bf16(a, b2, acc2, 0, 0, 0);
        acc3 = __builtin_amdgcn_mfma_f32_32x32x16_bf16(a, b3, acc3, 0, 0, 0);
    }

    int col = l & 31;
    int rbase = 4 * (l >> 5);
    floatx16 accs[4] = {acc0, acc1, acc2, acc3};
    for (int t4 = 0; t4 < 4; t4++) {
        int n = t4 * 32 + col;
        float bv = bias[n];
#pragma unroll
        for (int r = 0; r < 16; r++) {
            int row = (r & 3) + 8 * (r >> 2) + rbase;
            int gm = m0 + row;
            int gn = node0 + gm;
            if (gn >= N_NODES) continue;
            float v = accs[t4][r] + bv;
            v = (v >= 0.f) ? v : NEG_SLOPE * v;
            if (residual) v += bfraw2f(sA[gm * RS + 128 + n]);
            xout[(size_t)gn * DIM + n] = f2bf(v);
        }
    }
}

// ---------------- global mean pool, parallel segment-sum ----------------
__global__ __launch_bounds__(128) void pool_partial(const ushort* __restrict__ xb,
                                                    const int* __restrict__ batch,
                                                    float* __restrict__ pooled) {
    int nb = blockIdx.x * 128;
    int ne = min(nb + 128, N_NODES);
    int d = threadIdx.x;
    int gcur = batch[nb];
    float acc = 0.f;
    for (int n = nb; n < ne; n++) {
        int g = batch[n];
        if (g != gcur) {
            atomicAdd(&pooled[gcur * DIM + d], acc);
            acc = 0.f;
            gcur = g;
        }
        acc += bfraw2f(xb[(size_t)n * DIM + d]);
    }
    atomicAdd(&pooled[gcur * DIM + d], acc);
}

__global__ void pool_final(const float* __restrict__ pooled,
                           const int* __restrict__ gstart,
                           float* __restrict__ out) {
    int i = blockIdx.x * blockDim.x + threadIdx.x;
    if (i >= N_GRAPHS * DIM) return;
    int g = i >> 7;
    int cnt = gstart[g + 1] - gstart[g];
    out[i] = pooled[i] / (float)max(cnt, 1);
}

// ---------------- launch ----------------

extern "C" void kernel_launch(void* const* d_in, const int* in_sizes, int n_in,
                              void* d_out, int out_size, void* d_ws, size_t ws_size,
                              hipStream_t stream) {
    const float* x     = (const float*)d_in[0];
    const int*   ei    = (const int*)d_in[1];
    const int*   batch = (const int*)d_in[2];
    const float* Wl    = (const float*)d_in[3];
    const float* bl    = (const float*)d_in[4];
    const float* Wr    = (const float*)d_in[5];
    float* out = (float*)d_out;

    const int* esrc = ei;
    const int* edst = ei + N_EDGES;

    // workspace layout
    ushort* xb0  = (ushort*)d_ws;                         // [N,128] bf16
    ushort* xbuf = xb0 + (size_t)N_NODES * DIM;           // [N,128] bf16
    ushort* agg  = xbuf + (size_t)N_NODES * DIM;          // [N,128] bf16
    ushort* wpk  = agg + (size_t)N_NODES * DIM;           // [4][2][128*128] bf16
    int* deg    = (int*)(wpk + (size_t)N_LAYERS * 2 * DIM * DIM);
    int* fill   = deg + N_NODES;
    int* csr    = fill + N_NODES;
    int* rp     = csr + N_EDGES;
    int* gstart = rp + (N_NODES + 1);
    int* bsum   = gstart + (N_GRAPHS + 1);
    float* pooled = (float*)(bsum + NB_SCAN);             // [G,128] fp32

    zero_ints<<<(2 * N_NODES + 255) / 256, 256, 0, stream>>>(deg, 2 * N_NODES);
    zero_ints<<<(N_GRAPHS * DIM + 255) / 256, 256, 0, stream>>>((int*)pooled, N_GRAPHS * DIM);

    convert_x<<<(N_NODES * DIM / 8 + 255) / 256, 256, 0, stream>>>((const float4*)x, (uint4*)xb0);
    pack_w<<<dim3(32, 2, 4), 64, 0, stream>>>(Wl, Wr, wpk);
    count_deg<<<(N_EDGES + 255) / 256, 256, 0, stream>>>(edst, deg);

    scan_pass1<<<NB_SCAN, 256, 0, stream>>>(deg, bsum);
    scan_pass2<<<1, 256, 0, stream>>>(bsum);
    scan_pass3<<<NB_SCAN, 256, 0, stream>>>(deg, bsum, rp);

    fill_csr<<<(N_EDGES + 255) / 256, 256, 0, stream>>>(esrc, edst, rp, fill, csr);
    graph_start<<<(N_NODES + 255) / 256, 256, 0, stream>>>(batch, gstart);

    int agg_blocks = (N_NODES + 3) / 4;   // wave per node
    int gemm_blocks = (N_NODES + 127) / 128;
    for (int l = 0; l < N_LAYERS; l++) {
        const ushort* xin = (l == 0) ? xb0 : xbuf;
        agg_mean_wave4<<<agg_blocks, 256, 0, stream>>>((const uint4*)xin, rp, csr, (uint4*)agg);
        fused_layer_mfma<<<gemm_blocks, 256, 0, stream>>>(
            agg, xin, xbuf, wpk + (size_t)l * 2 * DIM * DIM,
            bl + (size_t)l * DIM, (l >= 2) ? 1 : 0);
    }

    pool_partial<<<(N_NODES + 127) / 128, 128, 0, stream>>>(xbuf, batch, pooled);
    pool_final<<<(N_GRAPHS * DIM + 255) / 256, 256, 0, stream>>>(pooled, gstart, out);
}

// Round 9
// 337.059 us; speedup vs baseline: 1.6391x; 1.0903x over previous
//
#include <hip/hip_runtime.h>

#define N_NODES 50000
#define N_EDGES 600000
#define DIM 128
#define N_LAYERS 4
#define N_GRAPHS 64
#define NEG_SLOPE 0.01f
#define NB_SCAN ((N_NODES + 255) / 256)   // 196
#define NB_CNT ((N_EDGES + 255) / 256)    // 2344
#define NC_CONV (N_NODES * DIM / 8 / 256) // 3125
#define NB_PACK 64
#define RS 264  // LDS row stride in bf16 elems: 256 data + 8 pad (16B mult)

typedef __attribute__((ext_vector_type(8))) short short8;
typedef __attribute__((ext_vector_type(16))) float floatx16;

__device__ __forceinline__ unsigned short f2bf(float f) {
    union { float f; unsigned u; } c; c.f = f;
    unsigned u = c.u;
    unsigned r = (u + 0x7FFFu + ((u >> 16) & 1u)) >> 16;
    return (unsigned short)r;
}
__device__ __forceinline__ float bfraw2f(unsigned short b) {
    union { unsigned u; float f; } c; c.u = ((unsigned)b) << 16;
    return c.f;
}
__device__ __forceinline__ float bflo(unsigned u) {
    union { unsigned u; float f; } c; c.u = u << 16; return c.f;
}
__device__ __forceinline__ float bfhi(unsigned u) {
    union { unsigned u; float f; } c; c.u = u & 0xFFFF0000u; return c.f;
}

// ---------------- zero deg+fill (adjacent) and pooled ----------------
__global__ void zero2(int* a, int na, int* b, int nb) {
    int i = blockIdx.x * blockDim.x + threadIdx.x;
    if (i < na) a[i] = 0;
    else if (i < na + nb) b[i - na] = 0;
}

// ---------------- merged: convert_x | pack_w | count_deg (grid-partitioned) ----
__global__ void preprocess(const float4* __restrict__ x, uint4* __restrict__ xb,
                           const float* __restrict__ Wl, const float* __restrict__ Wr,
                           ushort* __restrict__ wpk,
                           const int* __restrict__ edst, int* __restrict__ deg) {
    int b = blockIdx.x;
    if (b < NC_CONV) {
        int i = b * 256 + threadIdx.x;  // chunk of 8 floats
        float4 a = x[i * 2], c = x[i * 2 + 1];
        uint4 o;
        o.x = ((unsigned)f2bf(a.y) << 16) | f2bf(a.x);
        o.y = ((unsigned)f2bf(a.w) << 16) | f2bf(a.z);
        o.z = ((unsigned)f2bf(c.y) << 16) | f2bf(c.x);
        o.w = ((unsigned)f2bf(c.w) << 16) | f2bf(c.z);
        xb[i] = o;
    } else if (b < NC_CONV + NB_PACK) {
        // pack weights into MFMA B-fragment order.
        // u = ((layer*2+m)*8+s)*4+t ; lane l holds B[s*16+(l>>5)*8+j][t*32+(l&31)]
        int u = (b - NC_CONV) * 4 + (threadIdx.x >> 6);
        int l = threadIdx.x & 63;
        int layer = u >> 6, m = (u >> 5) & 1, s = (u >> 2) & 7, tt = u & 3;
        const float* W = ((m == 0) ? Wl : Wr) + (size_t)layer * DIM * DIM;
        int n = tt * 32 + (l & 31);
        int kb = s * 16 + (l >> 5) * 8;
        size_t off = ((size_t)u * 64 + l) * 8;
        for (int j = 0; j < 8; j++)
            wpk[off + j] = f2bf(W[n * DIM + kb + j]);
    } else {
        int e = (b - NC_CONV - NB_PACK) * 256 + threadIdx.x;
        if (e < N_EDGES) atomicAdd(&deg[edst[e]], 1);
    }
}

// ---------------- 3-pass exclusive scan of deg -> rp ----------------
__global__ void scan_pass1(const int* __restrict__ deg, int* __restrict__ bsum) {
    int i = blockIdx.x * 256 + threadIdx.x;
    int v = (i < N_NODES) ? deg[i] : 0;
    for (int off = 32; off > 0; off >>= 1) v += __shfl_down(v, off, 64);
    __shared__ int ws[4];
    int lane = threadIdx.x & 63, w = threadIdx.x >> 6;
    if (lane == 0) ws[w] = v;
    __syncthreads();
    if (threadIdx.x == 0) bsum[blockIdx.x] = ws[0] + ws[1] + ws[2] + ws[3];
}

__global__ void scan_pass2(int* __restrict__ bsum) {
    __shared__ int sm[256];
    int t = threadIdx.x;
    int v = (t < NB_SCAN) ? bsum[t] : 0;
    sm[t] = v;
    __syncthreads();
    for (int off = 1; off < 256; off <<= 1) {
        int u = (t >= off) ? sm[t - off] : 0;
        __syncthreads();
        sm[t] += u;
        __syncthreads();
    }
    if (t < NB_SCAN) bsum[t] = sm[t] - v;
}

__global__ void scan_pass3(const int* __restrict__ deg, const int* __restrict__ bsum,
                           int* __restrict__ rp) {
    int i = blockIdx.x * 256 + threadIdx.x;
    int v = (i < N_NODES) ? deg[i] : 0;
    int lane = threadIdx.x & 63, w = threadIdx.x >> 6;
    int s = v;
    for (int off = 1; off < 64; off <<= 1) {
        int t = __shfl_up(s, off, 64);
        if (lane >= off) s += t;
    }
    __shared__ int ws[4];
    if (lane == 63) ws[w] = s;
    __syncthreads();
    int wo = 0;
    for (int k = 0; k < 4; k++) wo += (k < w) ? ws[k] : 0;
    int incl = s + wo + bsum[blockIdx.x];
    if (i < N_NODES) rp[i + 1] = incl;
    if (i == 0) rp[0] = 0;
}

// ---------------- merged: fill_csr | graph_start ----------------
__global__ void fill_gstart(const int* __restrict__ src, const int* __restrict__ dst,
                            const int* __restrict__ rp, int* __restrict__ fill,
                            int* __restrict__ csr,
                            const int* __restrict__ batch, int* __restrict__ gstart) {
    int b = blockIdx.x;
    if (b < NB_CNT) {
        int e = b * 256 + threadIdx.x;
        if (e >= N_EDGES) return;
        int d = dst[e];
        int pos = atomicAdd(&fill[d], 1);
        csr[rp[d] + pos] = src[e];
    } else {
        int i = (b - NB_CNT) * 256 + threadIdx.x;
        if (i >= N_NODES) return;
        int g0 = batch[i];
        if (i == 0) {
            for (int g = 0; g <= g0; g++) gstart[g] = 0;
        } else {
            int p = batch[i - 1];
            for (int g = p + 1; g <= g0; g++) gstart[g] = i;
        }
        if (i == N_NODES - 1) {
            for (int g = g0 + 1; g <= N_GRAPHS; g++) gstart[g] = N_NODES;
        }
    }
}

// ---------------- aggregation: wave per node, dwordx4 gather (r8, at wall) -------
__global__ __launch_bounds__(256) void agg_mean_wave4(const uint4* __restrict__ x16B,
                                                      const int* __restrict__ rp,
                                                      const int* __restrict__ csr,
                                                      uint4* __restrict__ agg16B) {
    int wv = threadIdx.x >> 6, lane = threadIdx.x & 63;
    int node = blockIdx.x * 4 + wv;
    if (node >= N_NODES) return;
    int s = rp[node], e = rp[node + 1];
    int ll = lane & 15, eg = lane >> 4;
    float a0 = 0.f, a1 = 0.f, a2 = 0.f, a3 = 0.f, a4 = 0.f, a5 = 0.f, a6 = 0.f, a7 = 0.f;
    for (int base = s; base < e; base += 64) {
        int cnt = min(64, e - base);
        unsigned myidx = (base + lane < e) ? (unsigned)csr[base + lane] : 0u;
        for (int j = 0; j < cnt; j += 16) {
            uint4 v[4];
#pragma unroll
            for (int k = 0; k < 4; k++) {
                int sel = j + k * 4 + eg;
                unsigned idx = __shfl(myidx, sel, 64);
                v[k] = make_uint4(0u, 0u, 0u, 0u);
                if (sel < cnt) v[k] = x16B[(size_t)idx * 16 + ll];
            }
#pragma unroll
            for (int k = 0; k < 4; k++) {
                a0 += bflo(v[k].x); a1 += bfhi(v[k].x);
                a2 += bflo(v[k].y); a3 += bfhi(v[k].y);
                a4 += bflo(v[k].z); a5 += bfhi(v[k].z);
                a6 += bflo(v[k].w); a7 += bfhi(v[k].w);
            }
        }
    }
    a0 += __shfl_xor(a0, 16, 64); a0 += __shfl_xor(a0, 32, 64);
    a1 += __shfl_xor(a1, 16, 64); a1 += __shfl_xor(a1, 32, 64);
    a2 += __shfl_xor(a2, 16, 64); a2 += __shfl_xor(a2, 32, 64);
    a3 += __shfl_xor(a3, 16, 64); a3 += __shfl_xor(a3, 32, 64);
    a4 += __shfl_xor(a4, 16, 64); a4 += __shfl_xor(a4, 32, 64);
    a5 += __shfl_xor(a5, 16, 64); a5 += __shfl_xor(a5, 32, 64);
    a6 += __shfl_xor(a6, 16, 64); a6 += __shfl_xor(a6, 32, 64);
    a7 += __shfl_xor(a7, 16, 64); a7 += __shfl_xor(a7, 32, 64);
    if (eg == 0) {
        float inv = 1.0f / (float)max(e - s, 1);
        uint4 o;
        o.x = ((unsigned)f2bf(a1 * inv) << 16) | f2bf(a0 * inv);
        o.y = ((unsigned)f2bf(a3 * inv) << 16) | f2bf(a2 * inv);
        o.z = ((unsigned)f2bf(a5 * inv) << 16) | f2bf(a4 * inv);
        o.w = ((unsigned)f2bf(a7 * inv) << 16) | f2bf(a6 * inv);
        agg16B[(size_t)node * 16 + ll] = o;
    }
}

// ---------------- fused dual-GEMM layer, MFMA bf16, 64-node blocks ----------------
// 33.8 KB LDS -> 4 blocks/CU (16 waves). wave w: m-tile (w>>1), output half (w&1).
__global__ __launch_bounds__(256, 4) void fused_layer_mfma(const ushort* __restrict__ agg,
                                                           const ushort* __restrict__ xin,
                                                           ushort* __restrict__ xout,
                                                           const ushort* __restrict__ wpk,
                                                           const float* __restrict__ bias,
                                                           int residual) {
    __shared__ ushort sA[64 * RS];  // row r: [agg(128) | x(128) | pad(8)]
    int t = threadIdx.x;
    int node0 = blockIdx.x * 64;

    const uint4* aggv = (const uint4*)(agg + (size_t)node0 * DIM);
    const uint4* xv   = (const uint4*)(xin + (size_t)node0 * DIM);
    for (int i = t; i < 64 * 32; i += 256) {
        int r = i >> 5, c = i & 31;
        uint4 val = make_uint4(0u, 0u, 0u, 0u);
        if (node0 + r < N_NODES)
            val = (c < 16) ? aggv[r * 16 + c] : xv[r * 16 + (c - 16)];
        *(uint4*)&sA[r * RS + c * 8] = val;
    }
    __syncthreads();

    int w = t >> 6, l = t & 63;
    int m0 = (w >> 1) * 32;
    int th = w & 1;  // output half: t4 in {2*th, 2*th+1}
    const ushort* arow = &sA[(m0 + (l & 31)) * RS];
    int khalf = (l >> 5) * 8;

    floatx16 acc0, acc1;
    for (int ii = 0; ii < 16; ii++) acc0[ii] = acc1[ii] = 0.f;

    const ushort* wl8 = wpk + (size_t)l * 8 + (size_t)(2 * th) * 512;
#pragma unroll
    for (int s2 = 0; s2 < 16; s2++) {
        int m = s2 >> 3, s = s2 & 7;
        short8 a = *(const short8*)(arow + m * 128 + s * 16 + khalf);
        size_t fb = (size_t)((m * 8 + s) * 4) * 512;
        short8 b0 = *(const short8*)(wl8 + fb);
        short8 b1 = *(const short8*)(wl8 + fb + 512);
        acc0 = __builtin_amdgcn_mfma_f32_32x32x16_bf16(a, b0, acc0, 0, 0, 0);
        acc1 = __builtin_amdgcn_mfma_f32_32x32x16_bf16(a, b1, acc1, 0, 0, 0);
    }

    int col = l & 31;
    int rbase = 4 * (l >> 5);
    floatx16 accs[2] = {acc0, acc1};
    for (int ti = 0; ti < 2; ti++) {
        int n = (2 * th + ti) * 32 + col;
        float bv = bias[n];
#pragma unroll
        for (int r = 0; r < 16; r++) {
            int row = (r & 3) + 8 * (r >> 2) + rbase;
            int gm = m0 + row;
            int gn = node0 + gm;
            if (gn >= N_NODES) continue;
            float v = accs[ti][r] + bv;
            v = (v >= 0.f) ? v : NEG_SLOPE * v;
            if (residual) v += bfraw2f(sA[gm * RS + 128 + n]);
            xout[(size_t)gn * DIM + n] = f2bf(v);
        }
    }
}

// ---------------- global mean pool, parallel segment-sum ----------------
__global__ __launch_bounds__(128) void pool_partial(const ushort* __restrict__ xb,
                                                    const int* __restrict__ batch,
                                                    float* __restrict__ pooled) {
    int nb = blockIdx.x * 128;
    int ne = min(nb + 128, N_NODES);
    int d = threadIdx.x;
    int gcur = batch[nb];
    float acc = 0.f;
    for (int n = nb; n < ne; n++) {
        int g = batch[n];
        if (g != gcur) {
            atomicAdd(&pooled[gcur * DIM + d], acc);
            acc = 0.f;
            gcur = g;
        }
        acc += bfraw2f(xb[(size_t)n * DIM + d]);
    }
    atomicAdd(&pooled[gcur * DIM + d], acc);
}

__global__ void pool_final(const float* __restrict__ pooled,
                           const int* __restrict__ gstart,
                           float* __restrict__ out) {
    int i = blockIdx.x * blockDim.x + threadIdx.x;
    if (i >= N_GRAPHS * DIM) return;
    int g = i >> 7;
    int cnt = gstart[g + 1] - gstart[g];
    out[i] = pooled[i] / (float)max(cnt, 1);
}

// ---------------- launch ----------------

extern "C" void kernel_launch(void* const* d_in, const int* in_sizes, int n_in,
                              void* d_out, int out_size, void* d_ws, size_t ws_size,
                              hipStream_t stream) {
    const float* x     = (const float*)d_in[0];
    const int*   ei    = (const int*)d_in[1];
    const int*   batch = (const int*)d_in[2];
    const float* Wl    = (const float*)d_in[3];
    const float* bl    = (const float*)d_in[4];
    const float* Wr    = (const float*)d_in[5];
    float* out = (float*)d_out;

    const int* esrc = ei;
    const int* edst = ei + N_EDGES;

    // workspace layout
    ushort* xb0  = (ushort*)d_ws;                         // [N,128] bf16
    ushort* xbuf = xb0 + (size_t)N_NODES * DIM;           // [N,128] bf16
    ushort* agg  = xbuf + (size_t)N_NODES * DIM;          // [N,128] bf16
    ushort* wpk  = agg + (size_t)N_NODES * DIM;           // [4][2][128*128] bf16
    int* deg    = (int*)(wpk + (size_t)N_LAYERS * 2 * DIM * DIM);
    int* fill   = deg + N_NODES;
    int* csr    = fill + N_NODES;
    int* rp     = csr + N_EDGES;
    int* gstart = rp + (N_NODES + 1);
    int* bsum   = gstart + (N_GRAPHS + 1);
    float* pooled = (float*)(bsum + NB_SCAN);             // [G,128] fp32

    // 1. zero deg+fill (adjacent, 2N) and pooled (G*D)
    zero2<<<(2 * N_NODES + N_GRAPHS * DIM + 255) / 256, 256, 0, stream>>>(
        deg, 2 * N_NODES, (int*)pooled, N_GRAPHS * DIM);

    // 2. convert | pack | count (one grid)
    preprocess<<<NC_CONV + NB_PACK + NB_CNT, 256, 0, stream>>>(
        (const float4*)x, (uint4*)xb0, Wl, Wr, wpk, edst, deg);

    // 3. scan
    scan_pass1<<<NB_SCAN, 256, 0, stream>>>(deg, bsum);
    scan_pass2<<<1, 256, 0, stream>>>(bsum);
    scan_pass3<<<NB_SCAN, 256, 0, stream>>>(deg, bsum, rp);

    // 4. fill csr | graph segment starts
    fill_gstart<<<NB_CNT + NB_SCAN, 256, 0, stream>>>(esrc, edst, rp, fill, csr,
                                                      batch, gstart);

    // 5. layers
    int agg_blocks = (N_NODES + 3) / 4;
    int gemm_blocks = (N_NODES + 63) / 64;
    for (int l = 0; l < N_LAYERS; l++) {
        const ushort* xin = (l == 0) ? xb0 : xbuf;
        agg_mean_wave4<<<agg_blocks, 256, 0, stream>>>((const uint4*)xin, rp, csr, (uint4*)agg);
        fused_layer_mfma<<<gemm_blocks, 256, 0, stream>>>(
            agg, xin, xbuf, wpk + (size_t)l * 2 * DIM * DIM,
            bl + (size_t)l * DIM, (l >= 2) ? 1 : 0);
    }

    // 6. pool
    pool_partial<<<(N_NODES + 127) / 128, 128, 0, stream>>>(xbuf, batch, pooled);
    pool_final<<<(N_GRAPHS * DIM + 255) / 256, 256, 0, stream>>>(pooled, gstart, out);
}